// Round 6
// baseline (221.645 us; speedup 1.0000x reference)
//
#include <hip/hip_runtime.h>
#include <math.h>

// Problem constants
constexpr int Bn  = 2;
constexpr int Sn  = 4096;
constexpr int En  = 1024;
constexpr int Hn  = 16;
constexpr int Mtot = Bn * Sn;             // 8192
constexpr int Kp  = 1024;                 // GEMM K (fp16 single precision)
constexpr int QT   = 128;                 // queries per attention block
constexpr int NST  = 10;                  // key subtiles per block: (128+512)/64
constexpr int PADK = 68;                  // Kt/Vt row stride (bf16)
constexpr int PADP = 36;                  // Pt row stride (bf16)

typedef __bf16    bf16x8 __attribute__((ext_vector_type(8)));
typedef __bf16    bf16x4 __attribute__((ext_vector_type(4)));
typedef _Float16  f16x8  __attribute__((ext_vector_type(8)));
typedef _Float16  f16x4  __attribute__((ext_vector_type(4)));
typedef float     f32x4  __attribute__((ext_vector_type(4)));

// ---------------- fp32 -> fp16 conversion (verified r5) ----------------
__global__ void __launch_bounds__(256)
cvt_hs_kernel(const float* __restrict__ hs, _Float16* __restrict__ hs16)
{
    int t = blockIdx.x * 256 + threadIdx.x;
    int m = t >> 8;
    int k = (t & 255) << 2;
    float4 x = *(const float4*)&hs[((size_t)m << 10) + k];
    f16x4 h;
    h[0] = (_Float16)x.x; h[1] = (_Float16)x.y;
    h[2] = (_Float16)x.z; h[3] = (_Float16)x.w;
    *(f16x4*)&hs16[((size_t)m << 10) + k] = h;
}

__global__ void __launch_bounds__(256)
cvt_w_kernel(const float* __restrict__ qw, const float* __restrict__ kw,
             const float* __restrict__ vw, _Float16* __restrict__ w16)
{
    int t = blockIdx.x * 256 + threadIdx.x;
    int gn = t >> 8;
    int k  = (t & 255) << 2;
    int p  = gn >> 10, n = gn & 1023;
    const float* src = (p == 0) ? qw : (p == 1) ? kw : vw;
    float4 x = *(const float4*)&src[((size_t)n << 10) + k];
    f16x4 h;
    h[0] = (_Float16)x.x; h[1] = (_Float16)x.y;
    h[2] = (_Float16)x.z; h[3] = (_Float16)x.w;
    *(f16x4*)&w16[((size_t)gn << 10) + k] = h;
}

// ---------------- QKV projection: fp16 MFMA GEMM (verified r5, unchanged) ---
__device__ inline void load_lds16(const void* g, void* s) {
    __builtin_amdgcn_global_load_lds((const __attribute__((address_space(1))) void*)g,
                                     (__attribute__((address_space(3))) void*)s,
                                     16, 0, 0);
}

__global__ void __launch_bounds__(256)
qkv_mfma_kernel(const _Float16* __restrict__ A2, const _Float16* __restrict__ B2,
                const float* __restrict__ qb, const float* __restrict__ kb,
                const float* __restrict__ vb,
                __bf16* __restrict__ q16, __bf16* __restrict__ k16,
                __bf16* __restrict__ vt16)
{
    __shared__ _Float16 As[128 * 32];
    __shared__ _Float16 Bs[128 * 32];

    const int tid  = threadIdx.x;
    const int m0   = blockIdx.x * 128;     // seq tile
    const int n0   = blockIdx.y * 128;     // feature tile (0..3071)
    const int w    = tid >> 6;
    const int lane = tid & 63;
    const int wm   = w >> 1, wn = w & 1;
    const int mrow = lane & 15, quad = lane >> 4;

    const int stRow = w * 16 + (lane >> 2);
    const int stCol = (lane & 3) * 8;

    f32x4 acc[4][4] = {};

    const _Float16* Abase = A2 + (size_t)(m0 + stRow) * Kp + stCol;
    const _Float16* Bbase = B2 + (size_t)(n0 + stRow) * Kp + stCol;
    _Float16* AsW = &As[w * 512];
    _Float16* BsW = &Bs[w * 512];

    for (int k0 = 0; k0 < Kp; k0 += 32) {
        load_lds16(Abase + k0,            AsW);
        load_lds16(Abase + 64 * Kp + k0,  AsW + 2048);
        load_lds16(Bbase + k0,            BsW);
        load_lds16(Bbase + 64 * Kp + k0,  BsW + 2048);
        __syncthreads();
        f16x8 af[4], bfr[4];
#pragma unroll
        for (int t = 0; t < 4; t++) {
            af[t]  = *(const f16x8*)&As[(wm * 64 + t * 16 + mrow) * 32 + quad * 8];
            bfr[t] = *(const f16x8*)&Bs[(wn * 64 + t * 16 + mrow) * 32 + quad * 8];
        }
#pragma unroll
        for (int ti = 0; ti < 4; ti++)
#pragma unroll
            for (int tj = 0; tj < 4; tj++)
                acc[ti][tj] = __builtin_amdgcn_mfma_f32_16x16x32_f16(
                    af[ti], bfr[tj], acc[ti][tj], 0, 0, 0);
        __syncthreads();
    }

    const int p = n0 >> 10;
    const float* bptr = (p == 0) ? qb : (p == 1) ? kb : vb;
#pragma unroll
    for (int tj = 0; tj < 4; tj++) {
        const int n  = n0 + wn * 64 + tj * 16 + mrow;
        const float bv = bptr[n & 1023];
        const int hh = (n & 1023) >> 6, dd = n & 63;
#pragma unroll
        for (int ti = 0; ti < 4; ti++) {
            const int m  = m0 + wm * 64 + ti * 16 + quad * 4;   // + r
            const int bb = m >> 12, ss = m & 4095;
            const size_t bhh = (size_t)(bb * Hn + hh);
            if (p == 0) {
#pragma unroll
                for (int r = 0; r < 4; r++)
                    q16[(bhh * Sn + ss + r) * 64 + dd] =
                        (__bf16)((acc[ti][tj][r] + bv) * 0.125f);
            } else if (p == 1) {
#pragma unroll
                for (int r = 0; r < 4; r++)
                    k16[(bhh * Sn + ss + r) * 64 + dd] =
                        (__bf16)(acc[ti][tj][r] + bv);
            } else {
                bf16x4 pv4;
#pragma unroll
                for (int r = 0; r < 4; r++)
                    pv4[r] = (__bf16)(acc[ti][tj][r] + bv);
                *(bf16x4*)&vt16[(bhh * 64 + dd) * (size_t)Sn + ss] = pv4;
            }
        }
    }
}

// ---------------- Banded attention: 128q blocks, 4 blocks/CU ----------------
// Wave tile 32q x 64k. S^T = K.Q^T ; O^T = V^T.P^T (split into 32-key halves
// so Pt is half-size). Single-buffered Kt/Vt (LDS 29.7 KB total) + reg
// prefetch of next subtile. Fast path (no predicates) on interior subtiles.
__global__ void __launch_bounds__(256, 4)
banded_attn_kernel(const __bf16* __restrict__ q16, const __bf16* __restrict__ k16,
                   const __bf16* __restrict__ vt16, const int* __restrict__ mask,
                   float* __restrict__ out)
{
    __shared__ __bf16 Kt[64 * PADK];      // 8704 B
    __shared__ __bf16 Vt[64 * PADK];      // 8704 B
    __shared__ __bf16 Pt[4][32 * PADP];   // 9216 B (per-wave 32q x 32k halves)
    __shared__ float  Msh[704];           // 2816 B

    const int c = blockIdx.x, h = blockIdx.y, b = blockIdx.z;
    const int bh = b * Hn + h;
    const int i0 = c * QT;
    const int jwin0 = i0 - 256;
    const int tid  = threadIdx.x;
    const int wv   = tid >> 6;
    const int lane = tid & 63;
    const int quad = lane >> 4, mrow = lane & 15;

#pragma unroll
    for (int rep = 0; rep < 3; rep++) {
        int idx = rep * 256 + tid;
        if (idx < 640) {
            int jg = jwin0 + idx;
            float mv = 0.f;
            if (jg >= 0 && jg < Sn && mask[b * Sn + jg] != 0) mv = -10000.f;
            Msh[idx] = mv;
        }
    }

    // Q B-fragments (loop-invariant): queries i0 + 32*wv + 16*tjq + mrow
    bf16x8 qf[2][2];
    const __bf16* qbase = q16 + (((size_t)bh * Sn + i0 + wv * 32) << 6);
#pragma unroll
    for (int tjq = 0; tjq < 2; tjq++)
#pragma unroll
        for (int kc = 0; kc < 2; kc++)
            qf[tjq][kc] = *(const bf16x8*)(qbase + (16 * tjq + mrow) * 64 + 32 * kc + 8 * quad);

    const int sr = lane >> 3;      // 0..7
    const int sc = lane & 7;       // 16B chunk
    bf16x8 kreg0, kreg1, vreg0, vreg1;
    auto gload = [&](int st) {
        const int j0 = jwin0 + st * 64;
        const int r0 = wv * 16 + sr;
        const int r1 = wv * 16 + 8 + sr;
        int jk0 = j0 + r0; jk0 = jk0 < 0 ? 0 : (jk0 > Sn - 1 ? Sn - 1 : jk0);
        int jk1 = j0 + r1; jk1 = jk1 < 0 ? 0 : (jk1 > Sn - 1 ? Sn - 1 : jk1);
        kreg0 = *(const bf16x8*)&k16[(((size_t)bh * Sn + jk0) << 6) + sc * 8];
        kreg1 = *(const bf16x8*)&k16[(((size_t)bh * Sn + jk1) << 6) + sc * 8];
        int jv = j0 + sc * 8; jv = jv < 0 ? 0 : (jv > Sn - 8 ? Sn - 8 : jv);
        vreg0 = *(const bf16x8*)&vt16[((size_t)bh * 64 + r0) * Sn + jv];
        vreg1 = *(const bf16x8*)&vt16[((size_t)bh * 64 + r1) * Sn + jv];
    };
    auto swrite = [&]() {
        *(bf16x8*)&Kt[(wv * 16 + sr) * PADK + sc * 8]     = kreg0;
        *(bf16x8*)&Kt[(wv * 16 + 8 + sr) * PADK + sc * 8] = kreg1;
        *(bf16x8*)&Vt[(wv * 16 + sr) * PADK + sc * 8]     = vreg0;
        *(bf16x8*)&Vt[(wv * 16 + 8 + sr) * PADK + sc * 8] = vreg1;
    };

    f32x4 acc_o[4][2] = {};
    float lrun[2] = {0.f, 0.f};
    __bf16* Pw = &Pt[wv][0];
    const int stlo = wv >> 1;

    gload(0);
    for (int st = 0; st < NST; st++) {
        __syncthreads();               // everyone done reading previous tile
        swrite();
        __syncthreads();               // tile ready
        if (st + 1 < NST) gload(st + 1);   // next loads in flight over compute

        const int j0 = jwin0 + 64 * st;
        const bool activ = (st >= stlo) && (st <= stlo + 8) &&
                           (j0 + 63 >= 0) && (j0 < Sn);
        if (activ) {
            const bool fast = (st > stlo) && (st < stlo + 8) &&
                              (j0 >= 0) && (j0 + 63 < Sn);
#pragma unroll
            for (int half = 0; half < 2; half++) {
                // ---- S^T for keys [32*half, 32*half+32), P -> Pt half ----
#pragma unroll
                for (int t2 = 0; t2 < 2; t2++) {
                    const int ti = 2 * half + t2;
                    bf16x8 ak0 = *(const bf16x8*)&Kt[(16 * ti + mrow) * PADK + quad * 8];
                    bf16x8 ak1 = *(const bf16x8*)&Kt[(16 * ti + mrow) * PADK + 32 + quad * 8];
                    const int y0 = 64 * st + 16 * ti + 4 * quad;
                    f32x4 ms4 = *(const f32x4*)&Msh[y0];
#pragma unroll
                    for (int tjq = 0; tjq < 2; tjq++) {
                        f32x4 s = {};
                        s = __builtin_amdgcn_mfma_f32_16x16x32_bf16(ak0, qf[tjq][0], s, 0, 0, 0);
                        s = __builtin_amdgcn_mfma_f32_16x16x32_bf16(ak1, qf[tjq][1], s, 0, 0, 0);
                        bf16x4 pk;
                        float psum = 0.f;
                        if (fast) {
#pragma unroll
                            for (int r = 0; r < 4; r++) {
                                float pv = __expf(s[r] + ms4[r]);
                                psum += pv;
                                pk[r] = (__bf16)pv;
                            }
                        } else {
                            const int xq = 32 * wv + 16 * tjq + mrow;
#pragma unroll
                            for (int r = 0; r < 4; r++) {
                                const int y = y0 + r;
                                bool ok = ((unsigned)(y - xq) <= 512u) &
                                          ((unsigned)(jwin0 + y) < 4096u);
                                float pv = ok ? __expf(s[r] + ms4[r]) : 0.f;
                                psum += pv;
                                pk[r] = (__bf16)pv;
                            }
                        }
                        lrun[tjq] += psum;
                        *(bf16x4*)&Pw[(16 * tjq + mrow) * PADP + 16 * t2 + 4 * quad] = pk;
                    }
                }
                // ---- O^T += V^T[:,half] . P^T[half,:] ----
                bf16x8 av[4];
#pragma unroll
                for (int dt = 0; dt < 4; dt++)
                    av[dt] = *(const bf16x8*)&Vt[(16 * dt + mrow) * PADK + 32 * half + quad * 8];
#pragma unroll
                for (int tjq = 0; tjq < 2; tjq++) {
                    bf16x8 pf = *(const bf16x8*)&Pw[(16 * tjq + mrow) * PADP + quad * 8];
#pragma unroll
                    for (int dt = 0; dt < 4; dt++)
                        acc_o[dt][tjq] = __builtin_amdgcn_mfma_f32_16x16x32_bf16(
                            av[dt], pf, acc_o[dt][tjq], 0, 0, 0);
                }
            }
        }
    }

    // denominators: keys live across lane bits 4-5
    float inv[2];
#pragma unroll
    for (int tjq = 0; tjq < 2; tjq++) {
        float l = lrun[tjq];
        l += __shfl_xor(l, 16);
        l += __shfl_xor(l, 32);
        inv[tjq] = 1.0f / l;
    }
    // O^T C-layout: row = d = 16*dt + 4*quad + r, col = q = mrow
#pragma unroll
    for (int dt = 0; dt < 4; dt++)
#pragma unroll
        for (int tjq = 0; tjq < 2; tjq++) {
            f32x4 o = acc_o[dt][tjq];
            o[0] *= inv[tjq]; o[1] *= inv[tjq]; o[2] *= inv[tjq]; o[3] *= inv[tjq];
            float* dst = out + ((size_t)(b * Sn + i0 + wv * 32 + 16 * tjq + mrow)) * En
                             + h * 64 + 16 * dt + 4 * quad;
            *(f32x4*)dst = o;
        }
}

extern "C" void kernel_launch(void* const* d_in, const int* in_sizes, int n_in,
                              void* d_out, int out_size, void* d_ws, size_t ws_size,
                              hipStream_t stream) {
    const float* hs  = (const float*)d_in[0];
    const int*  mask = (const int*)d_in[1];
    const float* qw  = (const float*)d_in[2];
    const float* qb  = (const float*)d_in[3];
    const float* kw  = (const float*)d_in[4];
    const float* kb  = (const float*)d_in[5];
    const float* vw  = (const float*)d_in[6];
    const float* vb  = (const float*)d_in[7];
    float* out = (float*)d_out;

    _Float16* hs16 = (_Float16*)d_ws;
    _Float16* w16  = (_Float16*)((char*)d_ws + (size_t)16777216);
    __bf16*   q16  = (__bf16*)((char*)d_ws + (size_t)23068672);
    __bf16*   k16  = (__bf16*)((char*)d_ws + (size_t)39845888);
    __bf16*   vt16 = (__bf16*)((char*)d_ws + (size_t)56623104);

    cvt_hs_kernel<<<8192, 256, 0, stream>>>(hs, hs16);
    cvt_w_kernel <<<3072, 256, 0, stream>>>(qw, kw, vw, w16);

    dim3 pgrid(Mtot / 128, 3072 / 128);   // (64, 24)
    qkv_mfma_kernel<<<pgrid, 256, 0, stream>>>(hs16, w16, qb, kb, vb, q16, k16, vt16);

    dim3 agrid(Sn / QT, Hn, Bn);          // (32, 16, 2) = 1024 blocks
    banded_attn_kernel<<<agrid, 256, 0, stream>>>(q16, k16, vt16, mask, out);
}